// Round 15
// baseline (303.509 us; speedup 1.0000x reference)
//
#include <hip/hip_runtime.h>
#include <hip/hip_bf16.h>
#include <stdint.h>

#define NE    64
#define DIN   512
#define DOUT  512
#define TTOK  131072
#define BM    128
#define BN    256
#define BK    64
#define NKT   (DIN / BK)              // 8 K-tiles
#define TILES_TOTAL (TTOK / BM + NE)  // 1088
#define NXCD  8
#define TPX   (TILES_TOTAL / NXCD)    // 136

typedef __bf16 bf16x8_t __attribute__((ext_vector_type(8)));
typedef float  f32x4_t  __attribute__((ext_vector_type(4)));

// LDS 80 KB EXACTLY -> 2 blocks/CU (160/80):
//   A single buf: 16 KB (128 rows x 128B bf16)   [single-buffer is race-free:
//     write happens after ph3's LGKM0-before-BAR fence, see loop]
//   B dbuf: 2 x 32 KB (256 rows x 128B bf16)
// (row&7)<<4 XOR swizzle on 128B rows (R12/R14: conflicts == 0).
#define ABUF    0
#define BBUF(i) (16384 + (i) * 32768)
#define LDS_BYTES 81920

#define WAITV(n) asm volatile("s_waitcnt vmcnt(" #n ")" ::: "memory")
#define LGKM0()  asm volatile("s_waitcnt lgkmcnt(0)" ::: "memory")
#define SB() __builtin_amdgcn_sched_barrier(0)
#define BAR() __builtin_amdgcn_s_barrier()

// ws layout: ws[0] = ntiles; tile table (int4) at ws+4; bf16 weight at +32KB
#define WBF_OFF 32768

__global__ void setup_tiles(const int* __restrict__ cnt, int* __restrict__ ws) {
    int e = threadIdx.x;
    if (e >= NE) return;
    int off = 0, tbase = 0;
    for (int i = 0; i < e; ++i) {
        int c = cnt[i];
        off += c;
        tbase += (c + (BM - 1)) / BM;
    }
    int c = cnt[e];
    int nt = (c + (BM - 1)) / BM;
    int* tbl = ws + 4;
    for (int t = 0; t < nt; ++t) {
        int idx = tbase + t;
        tbl[4 * idx + 0] = e;
        tbl[4 * idx + 1] = off + t * BM;
        tbl[4 * idx + 2] = off + c;
        tbl[4 * idx + 3] = 0;
    }
    if (e == NE - 1) ws[0] = tbase + nt;
}

// weight fp32 -> bf16, streaming
__global__ __launch_bounds__(256) void wcvt(const float* __restrict__ w,
                                            __bf16* __restrict__ wbf) {
    const size_t stride = (size_t)gridDim.x * 256;
    size_t i = (size_t)blockIdx.x * 256 + threadIdx.x;
    const size_t n8 = (size_t)NE * DOUT * DIN / 8;
    for (; i < n8; i += stride) {
        f32x4_t a = *(const f32x4_t*)(w + i * 8);
        f32x4_t b = *(const f32x4_t*)(w + i * 8 + 4);
        bf16x8_t h;
#pragma unroll
        for (int j = 0; j < 4; ++j) {
            h[j]     = (__bf16)a[j];
            h[4 + j] = (__bf16)b[j];
        }
        *(bf16x8_t*)(wbf + i * 8) = h;
    }
}

__device__ __forceinline__ void gload16(const void* g, uint8_t* l) {
    __builtin_amdgcn_global_load_lds(
        (const __attribute__((address_space(1))) uint32_t*)g,
        (__attribute__((address_space(3))) uint32_t*)l, 16, 0, 0);
}

__global__ __launch_bounds__(512, 4) void moe_gemm(
    const float* __restrict__ inp,
    const __bf16* __restrict__ wbf,
    const float* __restrict__ bias,
    const int* __restrict__ ws,
    float* __restrict__ out)
{
    __shared__ __align__(16) uint8_t smem[LDS_BYTES];

    const int bid  = blockIdx.x;
    const int xcd  = bid & (NXCD - 1);
    const int slot = bid >> 3;                 // 0..271
    const int tile = xcd * TPX + (slot >> 1);
    const int n0   = (slot & 1) * BN;

    const int ntiles = ws[0];
    if (tile >= ntiles) return;
    const int4 ti = ((const int4*)(ws + 4))[tile];
    const int e = ti.x, row0 = ti.y, row_end = ti.z;

    const int tid  = threadIdx.x;
    const int lane = tid & 63;
    const int wave = tid >> 6;         // 0..7

    // ---- A staging: thread (arow = tid>>2, acn = tid&3) stages 2 x 16B
    // chunks {acn, acn+4} of its row: 4 f32x4 loads -> 2 swizzled ds_writes ----
    const int arow = tid >> 2;         // 0..127
    const int acn  = tid & 3;
    int agrow = row0 + arow;
    if (agrow > row_end - 1) agrow = row_end - 1;   // clamp (C-stores guarded)
    const float* asrc = inp + (size_t)agrow * DIN + acn * 8;
    const int aswz = (arow & 7) << 4;
    const int awoff0 = arow * 128 + ((acn * 16) ^ aswz);
    const int awoff1 = arow * 128 + (((acn + 4) * 16) ^ aswz);

    f32x4_t ra[4];
    auto issueAglb = [&](int tk) {
        const float* p = asrc + tk * BK;
        ra[0] = *(const f32x4_t*)(p);
        ra[1] = *(const f32x4_t*)(p + 4);
        ra[2] = *(const f32x4_t*)(p + 32);
        ra[3] = *(const f32x4_t*)(p + 36);
    };
    auto cvtWriteA = [&]() {
        bf16x8_t h0, h1;
#pragma unroll
        for (int j = 0; j < 4; ++j) {
            h0[j]     = (__bf16)ra[0][j];
            h0[4 + j] = (__bf16)ra[1][j];
            h1[j]     = (__bf16)ra[2][j];
            h1[4 + j] = (__bf16)ra[3][j];
        }
        *(bf16x8_t*)(smem + ABUF + awoff0) = h0;
        *(bf16x8_t*)(smem + ABUF + awoff1) = h1;
    };

    // ---- B staging: 4 gload16/wave per K-tile (256 rows x 128B), linear
    // dest, source-preswizzled (u = ac^dr; group base % 8 == 0) ----
    const int dr = lane >> 3;
    const int ac = lane & 7;
    const int u  = ac ^ dr;
    const __bf16* bsrc[4];
#pragma unroll
    for (int i = 0; i < 4; ++i) {
        int row = wave * 32 + i * 8 + dr;
        bsrc[i] = wbf + (size_t)(e * DOUT + n0 + row) * DIN + u * 8;
    }
    auto issueB = [&](int tk, int buf) {
        uint8_t* dst = smem + BBUF(buf) + wave * 4096;
#pragma unroll
        for (int i = 0; i < 4; ++i)
            gload16(bsrc[i] + tk * BK, dst + i * 1024);
    };

    // ---- compute: wave owns 64 rows x 64 cols (4 m-frags x 4 n-frags) ----
    const int wr = (wave >> 2) * 64;   // 2 M-bands
    const int wc = (wave & 3) * 64;    // 4 N-bands
    const int frow = lane & 15;
    const int kg   = lane >> 4;

    f32x4_t acc[4][4] = {};
    bf16x8_t bg[4][2], af[2];

    auto dsrB = [&](int buf) {
#pragma unroll
        for (int n = 0; n < 4; ++n) {
            const int row = wc + n * 16 + frow;
            const uint8_t* p = smem + BBUF(buf) + row * 128;
            const int sw = (row & 7) << 4;
#pragma unroll
            for (int ks = 0; ks < 2; ++ks)
                bg[n][ks] = *(const bf16x8_t*)(p + ((ks * 64 + kg * 16) ^ sw));
        }
    };
    auto dsrA = [&](int q) {
        const int row = wr + q * 16 + frow;
        const uint8_t* p = smem + ABUF + row * 128;
        const int sw = (row & 7) << 4;
#pragma unroll
        for (int ks = 0; ks < 2; ++ks)
            af[ks] = *(const bf16x8_t*)(p + ((ks * 64 + kg * 16) ^ sw));
    };
    auto mfmaQ = [&](int q) {
        __builtin_amdgcn_s_setprio(1);
#pragma unroll
        for (int ks = 0; ks < 2; ++ks)
#pragma unroll
            for (int n = 0; n < 4; ++n)
                acc[q][n] = __builtin_amdgcn_mfma_f32_16x16x32_bf16(
                    af[ks], bg[n][ks], acc[q][n], 0, 0, 0);
        __builtin_amdgcn_s_setprio(0);
    };

    // ---- prologue: A(0) regs -> LDS; B(0) DMA ----
    issueAglb(0);                     // FIFO: A x4 (oldest)
    issueB(0, 0);                     // FIFO: A x4, B x4
    WAITV(4); SB();                   // certify A(0) regs; B(0) flies
    cvtWriteA();
    LGKM0();                          // A writes landed
    WAITV(0); SB();                   // B(0) LDS-resident
    BAR();

    // ---- main: 8 K-tiles x 4 phases; ONE vmcnt drain per K-tile (ph3).
    // ph3 fence order: dsrA(3); LGKM0 (own reads done); BAR; then the A-slab
    // write for t+1 is race-free (single-buffered A). ----
#pragma unroll
    for (int t = 0; t < NKT; ++t) {
        const int bb = t & 1;
        // phase 0: launch B(t+1); read all B-frags + A-frag 0
        if (t + 1 < NKT) { issueB(t + 1, bb ^ 1); SB(); }
        dsrB(bb);
        dsrA(0); SB();
        BAR(); LGKM0(); SB();
        mfmaQ(0);
        BAR();
        // phase 1: launch A(t+1) reg loads; A-frag 1
        if (t + 1 < NKT) { issueAglb(t + 1); SB(); }
        dsrA(1); SB();
        BAR(); LGKM0(); SB();
        mfmaQ(1);
        BAR();
        // phase 2: A-frag 2
        dsrA(2); SB();
        BAR(); LGKM0(); SB();
        mfmaQ(2);
        BAR();
        // phase 3: A-frag 3; certify A(t+1)+B(t+1); rewrite A slab
        dsrA(3);
        LGKM0(); SB();                // own dsrA(3) data in regs BEFORE barrier
        BAR();
        if (t + 1 < NKT) {
            WAITV(0); SB();           // A(t+1) regs + B(t+1) DMA certified
            cvtWriteA();              // safe: all waves passed LGKM0+BAR
        }
        mfmaQ(3);
        if (t + 1 < NKT) { LGKM0(); } // own A-writes landed before barrier
        SB();
        BAR();
    }

    // ---- epilogue: C/D layout col = lane&15, row = (lane>>4)*4 + j [m89] ----
    const int crow = kg * 4;
    const int ccol = frow;
    float bv[4];
#pragma unroll
    for (int n = 0; n < 4; ++n)
        bv[n] = bias[e * DOUT + n0 + wc + n * 16 + ccol];
#pragma unroll
    for (int m = 0; m < 4; ++m) {
#pragma unroll
        for (int j = 0; j < 4; ++j) {
            const int grow = row0 + wr + m * 16 + crow + j;
            if (grow < row_end) {
                float* orow = out + (size_t)grow * DOUT + n0 + wc + ccol;
#pragma unroll
                for (int n = 0; n < 4; ++n)
                    orow[n * 16] = acc[m][n][j] + bv[n];
            }
        }
    }
}

extern "C" void kernel_launch(void* const* d_in, const int* in_sizes, int n_in,
                              void* d_out, int out_size, void* d_ws, size_t ws_size,
                              hipStream_t stream) {
    const float* inp    = (const float*)d_in[0];
    const float* weight = (const float*)d_in[1];
    const float* bias   = (const float*)d_in[2];
    const int* cnt      = (const int*)d_in[3];   // int64 in reference, delivered as int32
    float* out = (float*)d_out;
    int* ws = (int*)d_ws;
    __bf16* wbf = (__bf16*)((char*)d_ws + WBF_OFF);

    hipLaunchKernelGGL(setup_tiles, dim3(1), dim3(64), 0, stream, cnt, ws);
    hipLaunchKernelGGL(wcvt, dim3(2048), dim3(256), 0, stream, weight, wbf);
    hipLaunchKernelGGL(moe_gemm, dim3(TILES_TOTAL * 2), dim3(512), 0, stream,
                       inp, wbf, bias, ws, out);
}

// Round 16
// 185.818 us; speedup vs baseline: 1.6334x; 1.6334x over previous
//
#include <hip/hip_runtime.h>
#include <hip/hip_bf16.h>
#include <stdint.h>

#define NE    64
#define DIN   512
#define DOUT  512
#define TTOK  131072
#define BM    128
#define BN    256
#define BK    64
#define NKT   (DIN / BK)              // 8 K-tiles
#define TILES_TOTAL (TTOK / BM + NE)  // 1088
#define NXCD  8
#define TPX   (TILES_TOTAL / NXCD)    // 136

typedef __bf16 bf16x8_t __attribute__((ext_vector_type(8)));
typedef float  f32x4_t  __attribute__((ext_vector_type(4)));

// LDS 80 KB EXACTLY -> 2 blocks/CU:
//   A single slab: 16 KB (128 rows x 128B bf16) — rewritten only inside the
//     end-of-tile barrier pair (reg-staged ds_write, fence-ordered)
//   B dbuf: 2 x 32 KB (256 rows x 128B bf16) — gload_lds DMA
// (row&7)<<4 XOR swizzle on 128B rows (R12/R14: conflicts == 0).
#define ABUF    0
#define BBUF(i) (16384 + (i) * 32768)
#define LDS_BYTES 81920

#define WAITV(n) asm volatile("s_waitcnt vmcnt(" #n ")" ::: "memory")
#define LGKM0()  asm volatile("s_waitcnt lgkmcnt(0)" ::: "memory")
#define SB() __builtin_amdgcn_sched_barrier(0)
#define BAR() __builtin_amdgcn_s_barrier()

// ws layout: ws[0] = ntiles; tile table (int4) at ws+4; bf16 weight at +32KB
#define WBF_OFF 32768

__global__ void setup_tiles(const int* __restrict__ cnt, int* __restrict__ ws) {
    int e = threadIdx.x;
    if (e >= NE) return;
    int off = 0, tbase = 0;
    for (int i = 0; i < e; ++i) {
        int c = cnt[i];
        off += c;
        tbase += (c + (BM - 1)) / BM;
    }
    int c = cnt[e];
    int nt = (c + (BM - 1)) / BM;
    int* tbl = ws + 4;
    for (int t = 0; t < nt; ++t) {
        int idx = tbase + t;
        tbl[4 * idx + 0] = e;
        tbl[4 * idx + 1] = off + t * BM;
        tbl[4 * idx + 2] = off + c;
        tbl[4 * idx + 3] = 0;
    }
    if (e == NE - 1) ws[0] = tbase + nt;
}

// weight fp32 -> bf16, streaming
__global__ __launch_bounds__(256) void wcvt(const float* __restrict__ w,
                                            __bf16* __restrict__ wbf) {
    const size_t stride = (size_t)gridDim.x * 256;
    size_t i = (size_t)blockIdx.x * 256 + threadIdx.x;
    const size_t n8 = (size_t)NE * DOUT * DIN / 8;
    for (; i < n8; i += stride) {
        f32x4_t a = *(const f32x4_t*)(w + i * 8);
        f32x4_t b = *(const f32x4_t*)(w + i * 8 + 4);
        bf16x8_t h;
#pragma unroll
        for (int j = 0; j < 4; ++j) {
            h[j]     = (__bf16)a[j];
            h[4 + j] = (__bf16)b[j];
        }
        *(bf16x8_t*)(wbf + i * 8) = h;
    }
}

__device__ __forceinline__ void gload16(const void* g, uint8_t* l) {
    __builtin_amdgcn_global_load_lds(
        (const __attribute__((address_space(1))) uint32_t*)g,
        (__attribute__((address_space(3))) uint32_t*)l, 16, 0, 0);
}

__global__ __launch_bounds__(512, 4) void moe_gemm(
    const float* __restrict__ inp,
    const __bf16* __restrict__ wbf,
    const float* __restrict__ bias,
    const int* __restrict__ ws,
    float* __restrict__ out)
{
    __shared__ __align__(16) uint8_t smem[LDS_BYTES];

    const int bid  = blockIdx.x;
    const int xcd  = bid & (NXCD - 1);
    const int slot = bid >> 3;                 // 0..271
    const int tile = xcd * TPX + (slot >> 1);
    const int n0   = (slot & 1) * BN;

    const int ntiles = ws[0];
    if (tile >= ntiles) return;
    const int4 ti = ((const int4*)(ws + 4))[tile];
    const int e = ti.x, row0 = ti.y, row_end = ti.z;

    const int tid  = threadIdx.x;
    const int lane = tid & 63;
    const int wave = tid >> 6;         // 0..7

    // ---- A staging (R15's proven pattern): thread (arow=tid>>2, acn=tid&3)
    // stages chunks {acn, acn+4}: 4 f32x4 loads -> 2 swizzled ds_write_b128 ----
    const int arow = tid >> 2;         // 0..127
    const int acn  = tid & 3;
    int agrow = row0 + arow;
    if (agrow > row_end - 1) agrow = row_end - 1;   // clamp (C-stores guarded)
    const float* asrc = inp + (size_t)agrow * DIN + acn * 8;
    const int aswz = (arow & 7) << 4;
    const int awoff0 = arow * 128 + ((acn * 16) ^ aswz);
    const int awoff1 = arow * 128 + (((acn + 4) * 16) ^ aswz);

    f32x4_t ra[4];
    auto issueAglb = [&](int tk) {
        const float* p = asrc + tk * BK;
        ra[0] = *(const f32x4_t*)(p);
        ra[1] = *(const f32x4_t*)(p + 4);
        ra[2] = *(const f32x4_t*)(p + 32);
        ra[3] = *(const f32x4_t*)(p + 36);
    };
    auto cvtWriteA = [&]() {
        bf16x8_t h0, h1;
#pragma unroll
        for (int j = 0; j < 4; ++j) {
            h0[j]     = (__bf16)ra[0][j];
            h0[4 + j] = (__bf16)ra[1][j];
            h1[j]     = (__bf16)ra[2][j];
            h1[4 + j] = (__bf16)ra[3][j];
        }
        *(bf16x8_t*)(smem + ABUF + awoff0) = h0;
        *(bf16x8_t*)(smem + ABUF + awoff1) = h1;
    };

    // ---- B staging (R14-proven): 4 gload16/wave per K-tile, linear dest,
    // source-preswizzled (u = ac^dr; group base % 8 == 0) ----
    const int dr = lane >> 3;
    const int ac = lane & 7;
    const int u  = ac ^ dr;
    const __bf16* bsrc[4];
#pragma unroll
    for (int i = 0; i < 4; ++i) {
        int row = wave * 32 + i * 8 + dr;
        bsrc[i] = wbf + (size_t)(e * DOUT + n0 + row) * DIN + u * 8;
    }
    auto issueB = [&](int tk, int buf) {
        uint8_t* dst = smem + BBUF(buf) + wave * 4096;
#pragma unroll
        for (int i = 0; i < 4; ++i)
            gload16(bsrc[i] + tk * BK, dst + i * 1024);
    };

    // ---- compute: wave owns 64 rows x 64 cols (4 m-frags x 4 n-frags).
    // ks-major so only bg[4] (16 VGPR) is live — R15's bg[4][2] (32) spilled ----
    const int wr = (wave >> 2) * 64;   // 2 M-bands
    const int wc = (wave & 3) * 64;    // 4 N-bands
    const int frow = lane & 15;
    const int kg   = lane >> 4;

    f32x4_t acc[4][4] = {};

    auto computeTile = [&](int bb) {
#pragma unroll
        for (int ks = 0; ks < 2; ++ks) {
            bf16x8_t bg[4];
#pragma unroll
            for (int n = 0; n < 4; ++n) {
                const int row = wc + n * 16 + frow;
                bg[n] = *(const bf16x8_t*)(smem + BBUF(bb) + row * 128 +
                            ((ks * 64 + kg * 16) ^ ((row & 7) << 4)));
            }
#pragma unroll
            for (int q = 0; q < 4; ++q) {
                const int row = wr + q * 16 + frow;
                bf16x8_t af = *(const bf16x8_t*)(smem + ABUF + row * 128 +
                            ((ks * 64 + kg * 16) ^ ((row & 7) << 4)));
                __builtin_amdgcn_s_setprio(1);
#pragma unroll
                for (int n = 0; n < 4; ++n)
                    acc[q][n] = __builtin_amdgcn_mfma_f32_16x16x32_bf16(
                        af, bg[n], acc[q][n], 0, 0, 0);
                __builtin_amdgcn_s_setprio(0);
            }
        }
    };

    // ---- prologue ----
    issueAglb(0);                     // 4 loads (oldest)
    issueB(0, 0);                     // 4 DMA
    WAITV(4); SB();                   // certify A(0) regs; B(0) flies
    cvtWriteA();
    LGKM0();
    WAITV(0); SB();                   // B(0) LDS-resident
    BAR();

    // ---- main: 8 K-tiles, 2 barriers each, NO mid-tile syncs.
    // Per tile t: issue A(t+1) (4 loads, older) + B(t+1) DMA (4, newer);
    // one big compiler-scheduled window of 16 ds_read + 32 MFMA;
    // then: LGKM0 -> BAR (all reads of A-slab/B(bb) done) -> cvtWriteA
    // (auto-wait vmcnt(4): certifies A(t+1), B(t+1) keeps flying) ->
    // WAITV(0) (B(t+1), ~1 K-tile old) -> LGKM0 -> BAR. ----
#pragma unroll
    for (int t = 0; t < NKT; ++t) {
        const int bb = t & 1;
        if (t + 1 < NKT) {
            issueAglb(t + 1); SB();
            issueB(t + 1, bb ^ 1); SB();
        }
        computeTile(bb);
        if (t + 1 < NKT) {
            LGKM0(); SB();
            BAR();
            cvtWriteA();              // auto vmcnt(4): A(t+1) regs certified
            WAITV(0);                 // B(t+1) DMA landed
            LGKM0(); SB();            // own A-writes visible
            BAR();
        }
    }

    // ---- epilogue: C/D layout col = lane&15, row = (lane>>4)*4 + j [m89] ----
    const int crow = kg * 4;
    const int ccol = frow;
    float bv[4];
#pragma unroll
    for (int n = 0; n < 4; ++n)
        bv[n] = bias[e * DOUT + n0 + wc + n * 16 + ccol];
#pragma unroll
    for (int m = 0; m < 4; ++m) {
#pragma unroll
        for (int j = 0; j < 4; ++j) {
            const int grow = row0 + wr + m * 16 + crow + j;
            if (grow < row_end) {
                float* orow = out + (size_t)grow * DOUT + n0 + wc + ccol;
#pragma unroll
                for (int n = 0; n < 4; ++n)
                    orow[n * 16] = acc[m][n][j] + bv[n];
            }
        }
    }
}

extern "C" void kernel_launch(void* const* d_in, const int* in_sizes, int n_in,
                              void* d_out, int out_size, void* d_ws, size_t ws_size,
                              hipStream_t stream) {
    const float* inp    = (const float*)d_in[0];
    const float* weight = (const float*)d_in[1];
    const float* bias   = (const float*)d_in[2];
    const int* cnt      = (const int*)d_in[3];   // int64 in reference, delivered as int32
    float* out = (float*)d_out;
    int* ws = (int*)d_ws;
    __bf16* wbf = (__bf16*)((char*)d_ws + WBF_OFF);

    hipLaunchKernelGGL(setup_tiles, dim3(1), dim3(64), 0, stream, cnt, ws);
    hipLaunchKernelGGL(wcvt, dim3(2048), dim3(256), 0, stream, weight, wbf);
    hipLaunchKernelGGL(moe_gemm, dim3(TILES_TOTAL * 2), dim3(512), 0, stream,
                       inp, wbf, bias, ws, out);
}

// Round 17
// 180.733 us; speedup vs baseline: 1.6793x; 1.0281x over previous
//
#include <hip/hip_runtime.h>
#include <hip/hip_bf16.h>
#include <stdint.h>

#define NE    64
#define DIN   512
#define DOUT  512
#define TTOK  131072
#define BM    256
#define BN    256
#define BK    64
#define NKT   (DIN / BK)              // 8 K-tiles
#define TILES_TOTAL (TTOK / BM + NE)  // 576
#define NXCD  8
#define TPX   (TILES_TOTAL / NXCD)    // 72

typedef __bf16 bf16x8_t __attribute__((ext_vector_type(8)));
typedef float  f32x4_t  __attribute__((ext_vector_type(4)));

// LDS 64 KB -> 2 blocks/CU x 1024 thr = 32 waves/CU (full machine):
//   A slab: 32 KB (256 rows x 128B bf16), single-buffered, reg-staged
//   B slab: 32 KB (256 rows x 128B bf16), single-buffered, gload_lds DMA
// Single-buffering race-free: readers fence LGKM0 before BAR; writes after
// BAR; B-DMA drained (vmcnt 0) before the closing BAR.
// (row&7)<<4 XOR swizzle on 128B rows (R12/R14/R16: conflict-clean).
#define ABUF    0
#define BBUF    32768
#define LDS_BYTES 65536

#define WAITV(n) asm volatile("s_waitcnt vmcnt(" #n ")" ::: "memory")
#define LGKM0()  asm volatile("s_waitcnt lgkmcnt(0)" ::: "memory")
#define SB() __builtin_amdgcn_sched_barrier(0)
#define BAR() __builtin_amdgcn_s_barrier()

// ws layout: ws[0] = ntiles; tile table (int4) at ws+4; bf16 weight at +32KB
#define WBF_OFF 32768

__global__ void setup_tiles(const int* __restrict__ cnt, int* __restrict__ ws) {
    int e = threadIdx.x;
    if (e >= NE) return;
    int off = 0, tbase = 0;
    for (int i = 0; i < e; ++i) {
        int c = cnt[i];
        off += c;
        tbase += (c + (BM - 1)) / BM;
    }
    int c = cnt[e];
    int nt = (c + (BM - 1)) / BM;
    int* tbl = ws + 4;
    for (int t = 0; t < nt; ++t) {
        int idx = tbase + t;
        tbl[4 * idx + 0] = e;
        tbl[4 * idx + 1] = off + t * BM;
        tbl[4 * idx + 2] = off + c;
        tbl[4 * idx + 3] = 0;
    }
    if (e == NE - 1) ws[0] = tbase + nt;
}

// weight fp32 -> bf16, streaming
__global__ __launch_bounds__(256) void wcvt(const float* __restrict__ w,
                                            __bf16* __restrict__ wbf) {
    const size_t stride = (size_t)gridDim.x * 256;
    size_t i = (size_t)blockIdx.x * 256 + threadIdx.x;
    const size_t n8 = (size_t)NE * DOUT * DIN / 8;
    for (; i < n8; i += stride) {
        f32x4_t a = *(const f32x4_t*)(w + i * 8);
        f32x4_t b = *(const f32x4_t*)(w + i * 8 + 4);
        bf16x8_t h;
#pragma unroll
        for (int j = 0; j < 4; ++j) {
            h[j]     = (__bf16)a[j];
            h[4 + j] = (__bf16)b[j];
        }
        *(bf16x8_t*)(wbf + i * 8) = h;
    }
}

__device__ __forceinline__ void gload16(const void* g, uint8_t* l) {
    __builtin_amdgcn_global_load_lds(
        (const __attribute__((address_space(1))) uint32_t*)g,
        (__attribute__((address_space(3))) uint32_t*)l, 16, 0, 0);
}

__global__ __launch_bounds__(1024, 2) void moe_gemm(
    const float* __restrict__ inp,
    const __bf16* __restrict__ wbf,
    const float* __restrict__ bias,
    const int* __restrict__ ws,
    float* __restrict__ out)
{
    __shared__ __align__(16) uint8_t smem[LDS_BYTES];

    const int bid  = blockIdx.x;
    const int xcd  = bid & (NXCD - 1);
    const int slot = bid >> 3;                 // 0..143
    const int tile = xcd * TPX + (slot >> 1);
    const int n0   = (slot & 1) * BN;

    const int ntiles = ws[0];
    if (tile >= ntiles) return;
    const int4 ti = ((const int4*)(ws + 4))[tile];
    const int e = ti.x, row0 = ti.y, row_end = ti.z;

    const int tid  = threadIdx.x;
    const int lane = tid & 63;
    const int wave = tid >> 6;         // 0..15

    // ---- A staging: thread (arow = tid>>2, acn = tid&3) stages chunks
    // {acn, acn+4} of its row: 4 f32x4 loads -> 2 swizzled ds_write_b128 ----
    const int arow = tid >> 2;         // 0..255
    const int acn  = tid & 3;
    int agrow = row0 + arow;
    if (agrow > row_end - 1) agrow = row_end - 1;   // clamp (C-stores guarded)
    const float* asrc = inp + (size_t)agrow * DIN + acn * 8;
    const int aswz = (arow & 7) << 4;
    const int awoff0 = arow * 128 + ((acn * 16) ^ aswz);
    const int awoff1 = arow * 128 + (((acn + 4) * 16) ^ aswz);

    f32x4_t ra[4];
    auto issueAglb = [&](int tk) {
        const float* p = asrc + tk * BK;
        ra[0] = *(const f32x4_t*)(p);
        ra[1] = *(const f32x4_t*)(p + 4);
        ra[2] = *(const f32x4_t*)(p + 32);
        ra[3] = *(const f32x4_t*)(p + 36);
    };
    auto cvtWriteA = [&]() {
        bf16x8_t h0, h1;
#pragma unroll
        for (int j = 0; j < 4; ++j) {
            h0[j]     = (__bf16)ra[0][j];
            h0[4 + j] = (__bf16)ra[1][j];
            h1[j]     = (__bf16)ra[2][j];
            h1[4 + j] = (__bf16)ra[3][j];
        }
        *(bf16x8_t*)(smem + ABUF + awoff0) = h0;
        *(bf16x8_t*)(smem + ABUF + awoff1) = h1;
    };

    // ---- B staging: 2 gload16/wave per K-tile (256 rows x 128B), linear
    // dest, source-preswizzled (u = ac^dr; group base % 8 == 0) ----
    const int dr = lane >> 3;
    const int ac = lane & 7;
    const int u  = ac ^ dr;
    const __bf16* bsrc[2];
#pragma unroll
    for (int i = 0; i < 2; ++i) {
        int row = wave * 16 + i * 8 + dr;
        bsrc[i] = wbf + (size_t)(e * DOUT + n0 + row) * DIN + u * 8;
    }
    auto issueB = [&](int tk) {
        uint8_t* dst = smem + BBUF + wave * 2048;
#pragma unroll
        for (int i = 0; i < 2; ++i)
            gload16(bsrc[i] + tk * BK, dst + i * 1024);
    };

    // ---- compute: wave owns 64 rows x 64 cols (4 m x 4 n frags), ks-major
    // so only bg[4] live (R15 spill lesson) ----
    const int wr = (wave >> 2) * 64;   // 4 M-bands
    const int wc = (wave & 3) * 64;    // 4 N-bands
    const int frow = lane & 15;
    const int kg   = lane >> 4;

    f32x4_t acc[4][4] = {};

    auto computeTile = [&]() {
#pragma unroll
        for (int ks = 0; ks < 2; ++ks) {
            bf16x8_t bg[4];
#pragma unroll
            for (int n = 0; n < 4; ++n) {
                const int row = wc + n * 16 + frow;
                bg[n] = *(const bf16x8_t*)(smem + BBUF + row * 128 +
                            ((ks * 64 + kg * 16) ^ ((row & 7) << 4)));
            }
#pragma unroll
            for (int q = 0; q < 4; ++q) {
                const int row = wr + q * 16 + frow;
                bf16x8_t af = *(const bf16x8_t*)(smem + ABUF + row * 128 +
                            ((ks * 64 + kg * 16) ^ ((row & 7) << 4)));
                __builtin_amdgcn_s_setprio(1);
#pragma unroll
                for (int n = 0; n < 4; ++n)
                    acc[q][n] = __builtin_amdgcn_mfma_f32_16x16x32_bf16(
                        af, bg[n], acc[q][n], 0, 0, 0);
                __builtin_amdgcn_s_setprio(0);
            }
        }
    };

    // ---- prologue: A(0)+B(0) into the slabs ----
    issueAglb(0);                     // 4 loads (oldest)
    issueB(0);                        // 2 DMA (newest)
    WAITV(2); SB();                   // certify A(0) regs; B(0) flies
    cvtWriteA();
    WAITV(0);                         // B(0) LDS-resident
    LGKM0(); SB();
    BAR();

    // ---- main: 8 K-tiles, 2 barriers each, single-slab both operands.
    // Per tile t: issue A(t+1) reg loads (latency hidden under the 32-MFMA
    // window); compute; LGKM0+BAR (all reads retired); issue B(t+1) DMA
    // (slab readers done); cvtWriteA (auto vmcnt keeps B flying — A loads
    // are older); WAITV(0) drains B; LGKM0 publishes A; BAR. ----
#pragma unroll
    for (int t = 0; t < NKT; ++t) {
        if (t + 1 < NKT) { issueAglb(t + 1); SB(); }
        computeTile();
        if (t + 1 < NKT) {
            LGKM0(); SB();
            BAR();
            issueB(t + 1);            // FIFO: A(t+1) x4 older, B x2 newer
            cvtWriteA();              // auto-wait retires A x4, B stays
            WAITV(0);                 // B(t+1) landed
            LGKM0(); SB();            // A writes visible
            BAR();
        }
    }

    // ---- epilogue: C/D layout col = lane&15, row = (lane>>4)*4 + j [m89] ----
    const int crow = kg * 4;
    const int ccol = frow;
    float bv[4];
#pragma unroll
    for (int n = 0; n < 4; ++n)
        bv[n] = bias[e * DOUT + n0 + wc + n * 16 + ccol];
#pragma unroll
    for (int m = 0; m < 4; ++m) {
#pragma unroll
        for (int j = 0; j < 4; ++j) {
            const int grow = row0 + wr + m * 16 + crow + j;
            if (grow < row_end) {
                float* orow = out + (size_t)grow * DOUT + n0 + wc + ccol;
#pragma unroll
                for (int n = 0; n < 4; ++n)
                    orow[n * 16] = acc[m][n][j] + bv[n];
            }
        }
    }
}

extern "C" void kernel_launch(void* const* d_in, const int* in_sizes, int n_in,
                              void* d_out, int out_size, void* d_ws, size_t ws_size,
                              hipStream_t stream) {
    const float* inp    = (const float*)d_in[0];
    const float* weight = (const float*)d_in[1];
    const float* bias   = (const float*)d_in[2];
    const int* cnt      = (const int*)d_in[3];   // int64 in reference, delivered as int32
    float* out = (float*)d_out;
    int* ws = (int*)d_ws;
    __bf16* wbf = (__bf16*)((char*)d_ws + WBF_OFF);

    hipLaunchKernelGGL(setup_tiles, dim3(1), dim3(64), 0, stream, cnt, ws);
    hipLaunchKernelGGL(wcvt, dim3(2048), dim3(256), 0, stream, weight, wbf);
    hipLaunchKernelGGL(moe_gemm, dim3(TILES_TOTAL * 2), dim3(1024), 0, stream,
                       inp, wbf, bias, ws, out);
}